// Round 18
// baseline (135.738 us; speedup 1.0000x reference)
//
#include <hip/hip_runtime.h>
#include <stdint.h>

#define BB 4
#define NN 2048
#define CC 768
#define HH 12
#define DD 64
#define QSCALE 0.18033688011112042f   // D^-0.5 * log2(e), folded into Q

typedef __attribute__((ext_vector_type(2))) float f32x2;
typedef __attribute__((ext_vector_type(4))) float f32x4;
typedef __attribute__((ext_vector_type(16))) float f32x16;
typedef __attribute__((ext_vector_type(8))) short s16x8;

__device__ __forceinline__ unsigned short f2bf(float f){
  unsigned int x = __float_as_uint(f);
  x += 0x7fffu + ((x >> 16) & 1u);          // round-to-nearest-even
  return (unsigned short)(x >> 16);
}

__device__ __forceinline__ f32x4 mfma16(s16x8 a, s16x8 b, f32x4 c){
  return __builtin_amdgcn_mfma_f32_16x16x32_bf16(a, b, c, 0, 0, 0);
}
__device__ __forceinline__ f32x16 mfma32(s16x8 a, s16x8 b, f32x16 c){
  return __builtin_amdgcn_mfma_f32_32x32x16_bf16(a, b, c, 0, 0, 0);
}

__device__ __forceinline__ float fexp2(float x){
#if __has_builtin(__builtin_amdgcn_exp2f)
  return __builtin_amdgcn_exp2f(x);
#else
  float r; asm("v_exp_f32 %0, %1\n\ts_nop 1" : "=v"(r) : "v"(x)); return r;
#endif
}

__device__ __forceinline__ void gld16(void* lds, const void* g){
  __builtin_amdgcn_global_load_lds(
      (const __attribute__((address_space(1))) unsigned int*)g,
      (__attribute__((address_space(3))) unsigned int*)lds, 16, 0, 0);
}

// ---- fused prep: [0,6144) xm = bf16(x*mask); [6144,8448) cast weights;
//      [8448] per-batch kv compaction scan (cmap, ntile, npadf) -----------
#define PX_BLOCKS 6144            // BB*NN*CC/4/256
#define PW_BLOCKS 2304            // 4*CC*CC/4/256
__global__ void prep_all(const float* __restrict__ x, const float* __restrict__ mask,
                         const float* __restrict__ wq, const float* __restrict__ wp,
                         unsigned short* __restrict__ xm,
                         unsigned short* __restrict__ oq, unsigned short* __restrict__ op,
                         int* __restrict__ cmap, int* __restrict__ ntile,
                         float* __restrict__ npadf){
  const int blk = blockIdx.x, t = threadIdx.x;
  if (blk < PX_BLOCKS){
    int i = blk * 256 + t;                         // float4 group index
    float4 v = ((const float4*)x)[i];
    float m = mask[i / 192];                       // 768/4 = 192 groups per row
    ushort4 o;
    o.x = f2bf(v.x * m); o.y = f2bf(v.y * m);
    o.z = f2bf(v.z * m); o.w = f2bf(v.w * m);
    *(ushort4*)&xm[i * 4] = o;
  } else if (blk < PX_BLOCKS + PW_BLOCKS){
    int i = (blk - PX_BLOCKS) * 256 + t;
    const int nq = (3 * CC * CC) / 4;
    const float4* s; unsigned short* d; int j;
    if (i < nq){ s = (const float4*)wq; d = oq; j = i; }
    else       { s = (const float4*)wp; d = op; j = i - nq; }
    float4 v = s[j];
    ushort4 o;
    o.x = f2bf(v.x); o.y = f2bf(v.y); o.z = f2bf(v.z); o.w = f2bf(v.w);
    *(ushort4*)&d[j * 4] = o;
  } else {
    // per-batch compaction: wave wv covers exactly batch wv (64 thr x 32 tok
    // = 2048). cmap[tok] = within-batch compact pos (or -1 if masked).
    const int ln = t & 63, wv = t >> 6;
    const int base = t * 32;
    int cnt = 0;
    #pragma unroll
    for (int j = 0; j < 32; ++j) cnt += (mask[base + j] != 0.f) ? 1 : 0;
    int v = cnt;                                   // wave inclusive scan
    #pragma unroll
    for (int off = 1; off < 64; off <<= 1){
      int u = __shfl_up(v, off);
      if (ln >= off) v += u;
    }
    __shared__ int wsum[4];
    if (ln == 63) wsum[wv] = v;                    // batch count
    int o2 = v - cnt;                              // within-batch excl prefix
    for (int j = 0; j < 32; ++j){
      int tok = base + j;
      cmap[tok] = (mask[tok] != 0.f) ? o2++ : -1;
    }
    __syncthreads();
    if (t < BB){
      int nb = wsum[t];
      int nt = (nb + 63) >> 6;
      ntile[t] = nt;
      npadf[t] = (float)(nt * 64 - nb);            // pad keys (each adds 1 to l)
    }
  }
}

// ---- padzero: zero ONLY the read-but-unwritten pad region of compacted
// K/Vt — rows/cols [nact_b, ntile_b*64) per (b,h). ~0.8 MB vs 50 MB memsets.
__global__ __launch_bounds__(256) void padzero(const int* __restrict__ ntile,
                                               const float* __restrict__ npadf,
                                               unsigned short* __restrict__ Kg,
                                               unsigned short* __restrict__ Vtg){
  const int bh = blockIdx.x, b = bh / HH, t = threadIdx.x;
  const int nt = ntile[b];
  const int npad = (int)npadf[b];
  if (npad == 0) return;
  const int nact = nt * 64 - npad;
  unsigned short* Kb = Kg + (size_t)bh * NN * DD + (size_t)nact * DD;
  for (int i = t; i < npad * DD; i += 256) Kb[i] = 0;          // contiguous
  unsigned short* Vb = Vtg + (size_t)bh * DD * NN;
  for (int i = t; i < npad * DD; i += 256){
    int d = i / npad, c = i - d * npad;
    Vb[(size_t)d * NN + nact + c] = 0;
  }
}

// ---- C = A(row-major [M,K]) * B^T (B row-major [Nn,K]), bf16 MFMA -------
// r18: M-tile 128 -> 64 (tile 64x128). r17 diagnosed the loop as VMEM-
// latency-bound (conflicts 0 after swizzle, dur null): the lever is block
// parallelism. qkv grid 1152->2304 (9/CU), proj 384->768 (3/CU); LDS
// 24KB/block (6 blocks/CU cap). Per-wave: 32x64 output, acc[2][4].
// Same k order + fragment math -> bit-identical. Swizzle (r17) kept:
// source chunk and ds_read chunk both XOR (row>>1)&3; LDS dest linear.
// Structure ledger: BK=64 REVERTED (r15); dbuf single-barrier kept (r16).
template<int MODE>
__global__ __launch_bounds__(256) void gemm_bt(
    const unsigned short* __restrict__ A, const unsigned short* __restrict__ Bw,
    int Nn, int K,
    unsigned short* __restrict__ Qg, unsigned short* __restrict__ Kg,
    unsigned short* __restrict__ Vtg, float* __restrict__ Outg,
    const int* __restrict__ cmap)
{
  __shared__ __align__(16) unsigned short As[2][64 * 32];
  __shared__ __align__(16) unsigned short Bs[2][128 * 32];
  const int t = threadIdx.x, lane = t & 63, wid = t >> 6;
  const int wr = wid >> 1, wc = wid & 1;
  const int bm = blockIdx.x, bn = blockIdx.y;
  const unsigned short* Ag = A  + (size_t)bm * 64 * K;
  const unsigned short* Bg = Bw + (size_t)bn * 128 * K;
  f32x4 acc[2][4] = {};
  // B staging: 128x32 = 512 chunks, 2/thread; rows wid*32+(lane>>2), +16
  const int srowB = wid * 32 + (lane >> 2);
  // A staging: 64x32 = 256 chunks, 1/thread; chunk c = t, row = c>>2
  const int srowA = wid * 16 + (lane >> 2);
  // source chunk swizzle (both A and B): (row>>1)&3 = (lane>>3)&3
  const int scol = ((lane & 3) ^ ((lane >> 3) & 3)) * 8;
  const int ar = wr * 32 + (lane & 15);
  const int br = wc * 64 + (lane & 15);
  // read chunk swizzle: (row>>1)&3 = (lane>>1)&3 (mi/wr/ni/wc-independent)
  const int kks = ((lane >> 4) ^ ((lane >> 1) & 3)) * 8;
  const int soA  = wid * 1024 + lane * 16;         // LDS byte offsets (m104)
  const int soB0 = wid * 2048 + lane * 16;
  const int soB1 = soB0 + 1024;

  // prologue: stage tile 0 into buf 0
  gld16((char*)As[0] + soA,  Ag + (size_t)srowA * K        + scol);
  gld16((char*)Bs[0] + soB0, Bg + (size_t)srowB * K        + scol);
  gld16((char*)Bs[0] + soB1, Bg + (size_t)(srowB + 16) * K + scol);
  __syncthreads();                                 // drains vmcnt(0)

  const int NIT = K >> 5;
  int cur = 0;
  for (int it = 0; it < NIT; ++it){
    if (it + 1 < NIT){                             // stage next tile first
      const int k0 = (it + 1) << 5;
      char* An = (char*)As[cur ^ 1]; char* Bn = (char*)Bs[cur ^ 1];
      gld16(An + soA,  Ag + (size_t)srowA * K        + k0 + scol);
      gld16(Bn + soB0, Bg + (size_t)srowB * K        + k0 + scol);
      gld16(Bn + soB1, Bg + (size_t)(srowB + 16) * K + k0 + scol);
    }
    const unsigned short* Ac = As[cur];
    const unsigned short* Bc = Bs[cur];
    s16x8 af[2], bf[4];
    #pragma unroll
    for (int mi = 0; mi < 2; ++mi) af[mi] = *(const s16x8*)&Ac[(ar + mi * 16) * 32 + kks];
    #pragma unroll
    for (int ni = 0; ni < 4; ++ni) bf[ni] = *(const s16x8*)&Bc[(br + ni * 16) * 32 + kks];
    #pragma unroll
    for (int mi = 0; mi < 2; ++mi)
      #pragma unroll
      for (int ni = 0; ni < 4; ++ni)
        acc[mi][ni] = mfma16(af[mi], bf[ni], acc[mi][ni]);
    __syncthreads();   // reads of buf[cur] done + stage of buf[cur^1] landed
    cur ^= 1;
  }

  const int row0 = bm * 64 + wr * 32;
  const int col0 = bn * 128 + wc * 64;
  if (MODE == 0){
    #pragma unroll
    for (int ni = 0; ni < 4; ++ni){
      int col = col0 + ni * 16 + (lane & 15);
      int s = col / CC, rem = col - s * CC;
      int h = rem >> 6, d = rem & 63;
      #pragma unroll
      for (int mi = 0; mi < 2; ++mi){
        int rbase = row0 + mi * 16 + ((lane >> 4) << 2);
        int b = rbase >> 11, tok0 = rbase & 2047;
        if (s == 0){
          size_t base = (((size_t)(b * HH + h) << 11) + tok0) * DD + d;
          #pragma unroll
          for (int r = 0; r < 4; ++r) Qg[base + (size_t)r * DD] = f2bf(acc[mi][ni][r] * QSCALE);
        } else {
          int4 cj4 = *(const int4*)&cmap[rbase];
          #pragma unroll
          for (int r = 0; r < 4; ++r){
            int cj = (&cj4.x)[r];
            if (cj >= 0){
              if (s == 1)
                Kg [((size_t)(b * HH + h) * NN + cj) * DD + d] = f2bf(acc[mi][ni][r]);
              else
                Vtg[((size_t)(b * HH + h) * DD + d) * NN + cj] = f2bf(acc[mi][ni][r]);
            }
          }
        }
      }
    }
  } else {
    #pragma unroll
    for (int ni = 0; ni < 4; ++ni){
      int col = col0 + ni * 16 + (lane & 15);
      #pragma unroll
      for (int mi = 0; mi < 2; ++mi){
        int rbase = row0 + mi * 16 + ((lane >> 4) << 2);
        #pragma unroll
        for (int r = 0; r < 4; ++r) Outg[(size_t)(rbase + r) * Nn + col] = acc[mi][ni][r];
      }
    }
  }
}

// exp2 + RNE pack via v_cvt_pk_bf16_f32; l accumulated as float2 (v_pk_add_f32)
__device__ __forceinline__ void packrow2(float s0, float s1, float s2, float s3,
                                         f32x2& l2, unsigned& d0, unsigned& d1){
  float p0 = fexp2(s0), p1 = fexp2(s1), p2 = fexp2(s2), p3 = fexp2(s3);
  f32x2 a = {p0, p1}, b = {p2, p3};
  l2 += a + b;
  asm("v_cvt_pk_bf16_f32 %0, %1, %2" : "=v"(d0) : "v"(p0), "v"(p1));
  asm("v_cvt_pk_bf16_f32 %0, %1, %2" : "=v"(d1) : "v"(p2), "v"(p3));
}

// ---- flash attention over COMPACTED kv — byte-identical to r12/r14/r16/r17
// (verified): loop bound ntile[b] (~17 vs 32), l-correction npadf[b].
__global__ __launch_bounds__(256, 3) void attn_kernel(
    const unsigned short* __restrict__ Qg, const unsigned short* __restrict__ Kg,
    const unsigned short* __restrict__ Vtg, const float* __restrict__ mask,
    const int* __restrict__ ntile, const float* __restrict__ npadf,
    unsigned short* __restrict__ Og)
{
  // main loop: Ks 64x72 (9216B) + Vts 64x72 (9216B)
  // epilogue alias: 8192 f32 (o partials) + 128 f32 (l partials) = 33280B
  __shared__ __align__(16) char smem[33280];
  unsigned short* Ks  = (unsigned short*)smem;
  unsigned short* Vts = (unsigned short*)(smem + 9216);   // BYTE offset
  float* fb = (float*)smem;
  __shared__ float maskS[128];

  const int t = threadIdx.x, lane = t & 63, w = t >> 6;
  const int lo5 = lane & 31, hi = lane >> 5, hi8 = hi * 8;
  const int pair = w >> 1, h2 = w & 1;

  // XCD-chunked swizzle: 768 blocks = 8 x 96; all 16 q-tiles of a (b,h)
  // group land on one XCD -> K/V L2-resident per XCD.
  int g = blockIdx.x + (NN / 128) * blockIdx.y;
  g = (g & 7) * 96 + (g >> 3);
  const int qt = g & 15, bh = g >> 4;
  const int b = bh / HH, h = bh % HH;
  const unsigned short* Qb  = Qg  + (size_t)bh * NN * DD;
  const unsigned short* Kb  = Kg  + (size_t)bh * NN * DD;
  const unsigned short* Vtb = Vtg + (size_t)bh * DD * NN;
  const int ntiles = ntile[b];

  // Q fragments (B-operand of swapped QK^T), 2 q-groups of 32 rows
  const int qrow0 = qt * 128 + pair * 64 + lo5;
  s16x8 qf0[4], qf1[4];
  #pragma unroll
  for (int ds = 0; ds < 4; ++ds){
    qf0[ds] = *(const s16x8*)&Qb[(size_t)qrow0 * DD + ds * 16 + hi8];
    qf1[ds] = *(const s16x8*)&Qb[(size_t)(qrow0 + 32) * DD + ds * 16 + hi8];
  }
  if (t < 128) maskS[t] = mask[b * NN + qt * 128 + t];

  // staging: 64x64 tile, thread t handles rows r0, r0+32 (16B chunks)
  const int r0 = t >> 3, k8 = (t & 7) * 8;
  const int r1 = r0 + 32;

  f32x16 o00 = {}, o01 = {}, o10 = {}, o11 = {};   // [qgrp][d-half]
  f32x2 la0 = {0.f, 0.f}, la1 = {0.f, 0.f};

  s16x8 kA = *(const s16x8*)&Kb[(size_t)r0 * DD + k8];
  s16x8 kB = *(const s16x8*)&Kb[(size_t)r1 * DD + k8];
  s16x8 vA = *(const s16x8*)&Vtb[(size_t)r0 * NN + k8];
  s16x8 vB = *(const s16x8*)&Vtb[(size_t)(32 + r0) * NN + k8];

  const int kbase = (h2 * 32 + lo5) * 72 + hi8;     // K frag base (shorts)
  const int vcol  = h2 * 32 + hi8;                  // V frag col base

  for (int tt = 0; tt < ntiles; ++tt){
    *(s16x8*)&Ks [r0 * 72 + k8] = kA;
    *(s16x8*)&Ks [r1 * 72 + k8] = kB;
    *(s16x8*)&Vts[r0 * 72 + k8] = vA;
    *(s16x8*)&Vts[r1 * 72 + k8] = vB;
    __syncthreads();
    if (tt + 1 < ntiles){
      int nk = (tt + 1) * 64;
      kA = *(const s16x8*)&Kb[(size_t)(nk + r0) * DD + k8];
      kB = *(const s16x8*)&Kb[(size_t)(nk + r1) * DD + k8];
      vA = *(const s16x8*)&Vtb[(size_t)r0 * NN + nk + k8];
      vB = *(const s16x8*)&Vtb[(size_t)(32 + r0) * NN + nk + k8];
    }

    // QK^T swapped (kv half only): S^T[kv][q], col=q=lo5
    f32x16 s0 = {}, s1 = {};
    __builtin_amdgcn_s_setprio(1);
    #pragma unroll
    for (int ds = 0; ds < 4; ++ds){
      s16x8 kf = *(const s16x8*)&Ks[kbase + ds * 16];
      s0 = mfma32(kf, qf0[ds], s0);
      s1 = mfma32(kf, qf1[ds], s1);
    }
    __builtin_amdgcn_s_setprio(0);

    unsigned pdw0[8], pdw1[8];
    #pragma unroll
    for (int c = 0; c < 4; ++c){
      packrow2(s0[4*c+0], s0[4*c+1], s0[4*c+2], s0[4*c+3], la0, pdw0[2*c], pdw0[2*c+1]);
      packrow2(s1[4*c+0], s1[4*c+1], s1[4*c+2], s1[4*c+3], la1, pdw1[2*c], pdw1[2*c+1]);
    }

    // P-exchange + PV (2 k-slices of 16 in this wave's kv half)
    __builtin_amdgcn_s_setprio(1);
    #pragma unroll
    for (int sl = 0; sl < 2; ++sl){
      const int bb2 = sl * 4;
      unsigned X0 = pdw0[bb2+0], X1 = pdw0[bb2+1], Y0 = pdw0[bb2+2], Y1 = pdw0[bb2+3];
      asm("s_nop 0\n\tv_permlane32_swap_b32 %0, %1" : "+v"(X0), "+v"(Y0));
      asm("s_nop 0\n\tv_permlane32_swap_b32 %0, %1" : "+v"(X1), "+v"(Y1));
      union { unsigned u[4]; s16x8 v; } pa0;
      pa0.u[0] = X0; pa0.u[1] = X1; pa0.u[2] = Y0; pa0.u[3] = Y1;
      unsigned Z0 = pdw1[bb2+0], Z1 = pdw1[bb2+1], W0 = pdw1[bb2+2], W1 = pdw1[bb2+3];
      asm("s_nop 0\n\tv_permlane32_swap_b32 %0, %1" : "+v"(Z0), "+v"(W0));
      asm("s_nop 0\n\tv_permlane32_swap_b32 %0, %1" : "+v"(Z1), "+v"(W1));
      union { unsigned u[4]; s16x8 v; } pa1;
      pa1.u[0] = Z0; pa1.u[1] = Z1; pa1.u[2] = W0; pa1.u[3] = W1;
      s16x8 vfA = *(const s16x8*)&Vts[(size_t)lo5 * 72 + vcol + sl * 16];        // d 0..31
      s16x8 vfB = *(const s16x8*)&Vts[(size_t)(32 + lo5) * 72 + vcol + sl * 16]; // d 32..63
      o00 = mfma32(pa0.v, vfA, o00);
      o01 = mfma32(pa0.v, vfB, o01);
      o10 = mfma32(pa1.v, vfA, o10);
      o11 = mfma32(pa1.v, vfB, o11);
    }
    __builtin_amdgcn_s_setprio(0);
    __syncthreads();
  }

  // l partial per q (this wave's kv half): sum own 16 + partner-hi 16
  float lw0 = la0.x + la0.y; lw0 += __shfl_xor(lw0, 32);
  float lw1 = la1.x + la1.y; lw1 += __shfl_xor(lw1, 32);

  __syncthreads();                       // main-loop LDS reads done
  if (h2 == 1){                          // odd wave: publish partials
    const int ob = pair * 4096 + lane * 16;
    *(f32x16*)&fb[ob +    0] = o00;
    *(f32x16*)&fb[ob + 1024] = o01;
    *(f32x16*)&fb[ob + 2048] = o10;
    *(f32x16*)&fb[ob + 3072] = o11;
    if (hi == 0){
      fb[8192 + pair * 64 + lo5]      = lw0;
      fb[8192 + pair * 64 + 32 + lo5] = lw1;
    }
  }
  __syncthreads();
  if (h2 == 0){                          // even wave: combine + normalize + store
    const int ob = pair * 4096 + lane * 16;
    o00 += *(const f32x16*)&fb[ob +    0];
    o01 += *(const f32x16*)&fb[ob + 1024];
    o10 += *(const f32x16*)&fb[ob + 2048];
    o11 += *(const f32x16*)&fb[ob + 3072];
    float npad = npadf[b];
    lw0 = lw0 + fb[8192 + pair * 64 + lo5]      - npad;
    lw1 = lw1 + fb[8192 + pair * 64 + 32 + lo5] - npad;
    #pragma unroll
    for (int i = 0; i < 16; ++i){
      int q_ = (i & 3) + 8 * (i >> 2) + 4 * hi;
      int qg0 = qt * 128 + pair * 64 + q_;
      float lq0 = __shfl(lw0, q_);
      float mq0 = maskS[pair * 64 + q_];
      size_t base0 = ((size_t)b * NN + qg0) * CC + h * DD + lo5;
      if (mq0 != 0.f){
        float inv0 = mq0 / lq0;
        Og[base0]      = f2bf(o00[i] * inv0);
        Og[base0 + 32] = f2bf(o01[i] * inv0);
      } else {
        Og[base0] = 0; Og[base0 + 32] = 0;
      }
      float lq1 = __shfl(lw1, q_);
      float mq1 = maskS[pair * 64 + 32 + q_];
      size_t base1 = base0 + (size_t)32 * CC;
      if (mq1 != 0.f){
        float inv1 = mq1 / lq1;
        Og[base1]      = f2bf(o10[i] * inv1);
        Og[base1 + 32] = f2bf(o11[i] * inv1);
      } else {
        Og[base1] = 0; Og[base1 + 32] = 0;
      }
    }
  }
}

extern "C" void kernel_launch(void* const* d_in, const int* in_sizes, int n_in,
                              void* d_out, int out_size, void* d_ws, size_t ws_size,
                              hipStream_t stream){
  const float* x     = (const float*)d_in[0];
  const float* mask  = (const float*)d_in[1];
  const float* wqkv  = (const float*)d_in[2];
  const float* wproj = (const float*)d_in[3];
  float* out = (float*)d_out;
  char* ws = (char*)d_ws;
  size_t off = 0;
  auto alloc = [&](size_t bytes) -> void* {
    void* p = ws + off; off += (bytes + 255) & ~(size_t)255; return p;
  };
  unsigned short* xm  = (unsigned short*)alloc((size_t)BB * NN * CC * 2);
  unsigned short* wqb = (unsigned short*)alloc((size_t)3 * CC * CC * 2);
  unsigned short* wpb = (unsigned short*)alloc((size_t)CC * CC * 2);
  unsigned short* Qg  = (unsigned short*)alloc((size_t)BB * HH * NN * DD * 2);
  unsigned short* Kg  = (unsigned short*)alloc((size_t)BB * HH * NN * DD * 2);
  unsigned short* Vtg = (unsigned short*)alloc((size_t)BB * HH * NN * DD * 2);
  unsigned short* Og  = (unsigned short*)alloc((size_t)BB * NN * CC * 2);
  int* cmap           = (int*)alloc((size_t)BB * NN * sizeof(int));
  int* ntile          = (int*)alloc(BB * sizeof(int));
  float* npadf        = (float*)alloc(BB * sizeof(float));

  hipLaunchKernelGGL(prep_all, dim3(PX_BLOCKS + PW_BLOCKS + 1), dim3(256), 0, stream,
                     x, mask, wqkv, wproj, xm, wqb, wpb, cmap, ntile, npadf);
  hipLaunchKernelGGL(padzero, dim3(BB * HH), dim3(256), 0, stream,
                     ntile, npadf, Kg, Vtg);
  hipLaunchKernelGGL(gemm_bt<0>, dim3(BB * NN / 64, 3 * CC / 128), dim3(256), 0, stream,
                     xm, wqb, 3 * CC, CC, Qg, Kg, Vtg, (float*)nullptr, cmap);
  hipLaunchKernelGGL(attn_kernel, dim3(NN / 128, BB * HH), dim3(256), 0, stream,
                     Qg, Kg, Vtg, mask, ntile, npadf, Og);
  hipLaunchKernelGGL(gemm_bt<1>, dim3(BB * NN / 64, CC / 128), dim3(256), 0, stream,
                     Og, wpb, CC, CC, (unsigned short*)nullptr, (unsigned short*)nullptr,
                     (unsigned short*)nullptr, out, cmap);
}

// Round 19
// 134.834 us; speedup vs baseline: 1.0067x; 1.0067x over previous
//
#include <hip/hip_runtime.h>
#include <stdint.h>

#define BB 4
#define NN 2048
#define CC 768
#define HH 12
#define DD 64
#define QSCALE 0.18033688011112042f   // D^-0.5 * log2(e), folded into Q

typedef __attribute__((ext_vector_type(2))) float f32x2;
typedef __attribute__((ext_vector_type(4))) float f32x4;
typedef __attribute__((ext_vector_type(16))) float f32x16;
typedef __attribute__((ext_vector_type(8))) short s16x8;

__device__ __forceinline__ unsigned short f2bf(float f){
  unsigned int x = __float_as_uint(f);
  x += 0x7fffu + ((x >> 16) & 1u);          // round-to-nearest-even
  return (unsigned short)(x >> 16);
}

__device__ __forceinline__ f32x4 mfma16(s16x8 a, s16x8 b, f32x4 c){
  return __builtin_amdgcn_mfma_f32_16x16x32_bf16(a, b, c, 0, 0, 0);
}
__device__ __forceinline__ f32x16 mfma32(s16x8 a, s16x8 b, f32x16 c){
  return __builtin_amdgcn_mfma_f32_32x32x16_bf16(a, b, c, 0, 0, 0);
}

__device__ __forceinline__ float fexp2(float x){
#if __has_builtin(__builtin_amdgcn_exp2f)
  return __builtin_amdgcn_exp2f(x);
#else
  float r; asm("v_exp_f32 %0, %1\n\ts_nop 1" : "=v"(r) : "v"(x)); return r;
#endif
}

__device__ __forceinline__ void gld16(void* lds, const void* g){
  __builtin_amdgcn_global_load_lds(
      (const __attribute__((address_space(1))) unsigned int*)g,
      (__attribute__((address_space(3))) unsigned int*)lds, 16, 0, 0);
}

// ---- fused prep: [0,6144) xm = bf16(x*mask); [6144,8448) cast weights;
//      [8448] per-batch kv compaction scan (cmap, ntile, npadf) -----------
#define PX_BLOCKS 6144            // BB*NN*CC/4/256
#define PW_BLOCKS 2304            // 4*CC*CC/4/256
__global__ void prep_all(const float* __restrict__ x, const float* __restrict__ mask,
                         const float* __restrict__ wq, const float* __restrict__ wp,
                         unsigned short* __restrict__ xm,
                         unsigned short* __restrict__ oq, unsigned short* __restrict__ op,
                         int* __restrict__ cmap, int* __restrict__ ntile,
                         float* __restrict__ npadf){
  const int blk = blockIdx.x, t = threadIdx.x;
  if (blk < PX_BLOCKS){
    int i = blk * 256 + t;                         // float4 group index
    float4 v = ((const float4*)x)[i];
    float m = mask[i / 192];                       // 768/4 = 192 groups per row
    ushort4 o;
    o.x = f2bf(v.x * m); o.y = f2bf(v.y * m);
    o.z = f2bf(v.z * m); o.w = f2bf(v.w * m);
    *(ushort4*)&xm[i * 4] = o;
  } else if (blk < PX_BLOCKS + PW_BLOCKS){
    int i = (blk - PX_BLOCKS) * 256 + t;
    const int nq = (3 * CC * CC) / 4;
    const float4* s; unsigned short* d; int j;
    if (i < nq){ s = (const float4*)wq; d = oq; j = i; }
    else       { s = (const float4*)wp; d = op; j = i - nq; }
    float4 v = s[j];
    ushort4 o;
    o.x = f2bf(v.x); o.y = f2bf(v.y); o.z = f2bf(v.z); o.w = f2bf(v.w);
    *(ushort4*)&d[j * 4] = o;
  } else {
    // per-batch compaction: wave wv covers exactly batch wv (64 thr x 32 tok
    // = 2048). cmap[tok] = within-batch compact pos (or -1 if masked).
    const int ln = t & 63, wv = t >> 6;
    const int base = t * 32;
    int cnt = 0;
    #pragma unroll
    for (int j = 0; j < 32; ++j) cnt += (mask[base + j] != 0.f) ? 1 : 0;
    int v = cnt;                                   // wave inclusive scan
    #pragma unroll
    for (int off = 1; off < 64; off <<= 1){
      int u = __shfl_up(v, off);
      if (ln >= off) v += u;
    }
    __shared__ int wsum[4];
    if (ln == 63) wsum[wv] = v;                    // batch count
    int o2 = v - cnt;                              // within-batch excl prefix
    for (int j = 0; j < 32; ++j){
      int tok = base + j;
      cmap[tok] = (mask[tok] != 0.f) ? o2++ : -1;
    }
    __syncthreads();
    if (t < BB){
      int nb = wsum[t];
      int nt = (nb + 63) >> 6;
      ntile[t] = nt;
      npadf[t] = (float)(nt * 64 - nb);            // pad keys (each adds 1 to l)
    }
  }
}

// ---- padzero: zero ONLY the read-but-unwritten pad region of compacted
// K/Vt — rows/cols [nact_b, ntile_b*64) per (b,h). ~0.8 MB vs 50 MB memsets.
__global__ __launch_bounds__(256) void padzero(const int* __restrict__ ntile,
                                               const float* __restrict__ npadf,
                                               unsigned short* __restrict__ Kg,
                                               unsigned short* __restrict__ Vtg){
  const int bh = blockIdx.x, b = bh / HH, t = threadIdx.x;
  const int nt = ntile[b];
  const int npad = (int)npadf[b];
  if (npad == 0) return;
  const int nact = nt * 64 - npad;
  unsigned short* Kb = Kg + (size_t)bh * NN * DD + (size_t)nact * DD;
  for (int i = t; i < npad * DD; i += 256) Kb[i] = 0;          // contiguous
  unsigned short* Vb = Vtg + (size_t)bh * DD * NN;
  for (int i = t; i < npad * DD; i += 256){
    int d = i / npad, c = i - d * npad;
    Vb[(size_t)d * NN + nact + c] = 0;
  }
}

// ---- C = A(row-major [M,K]) * B^T (B row-major [Nn,K]), bf16 MFMA -------
// r19: BK=64 WITH proper both-sides XOR swizzle (fixes r15's failure mode).
// 128B LDS rows = 8 chunks; physical chunk p = c ^ (row&7) -> each 16-lane
// fragment read spreads over all 8 bank groups (2 addr/group = the 1024B/
// wave minimum, conflict-free). Staging: LDS dest LINEAR (m104); global
// source chunk c = (lane&7)^(lane>>3) of row (wid*4+j)*8+(lane>>3).
// Combined with r16's single-barrier dbuf: 12 barriers (vs 24), 32 MFMA
// per stage+barrier cycle. LDS 64KB -> 2 blocks/CU = 8 waves ≈ measured
// r17 occupancy (7.4 waves) — no loss. k order ascending -> bit-identical.
// Ledger: M64 tile (r18) REVERTED (+6.7us: fewer MFMA per barrier cycle);
// BK64-unswizzled (r15) REVERTED (conflicts 3x); dbuf kept (r16, -3.5us);
// swizzle kept (r17, conflicts->0, proves conflict-freedom mechanism).
template<int MODE>
__global__ __launch_bounds__(256) void gemm_bt(
    const unsigned short* __restrict__ A, const unsigned short* __restrict__ Bw,
    int Nn, int K,
    unsigned short* __restrict__ Qg, unsigned short* __restrict__ Kg,
    unsigned short* __restrict__ Vtg, float* __restrict__ Outg,
    const int* __restrict__ cmap)
{
  __shared__ __align__(16) unsigned short As[2][128 * 64];
  __shared__ __align__(16) unsigned short Bs[2][128 * 64];
  const int t = threadIdx.x, lane = t & 63, wid = t >> 6;
  const int wr = wid >> 1, wc = wid & 1;
  const int bm = blockIdx.x, bn = blockIdx.y;
  const unsigned short* Ag = A  + (size_t)bm * 128 * K;
  const unsigned short* Bg = Bw + (size_t)bn * 128 * K;
  f32x4 acc[4][4] = {};
  // staging (per matrix): 128 rows x 8 chunks = 1024 chunks; wave wid call j
  // writes LDS chunks [(wid*4+j)*64 + lane]. Source row/col for that slot:
  const int sr3 = lane >> 3;                       // row low bits
  const int scol = ((lane & 7) ^ sr3) * 8;         // swizzled source chunk
  int srow[4], ldso[4];
  #pragma unroll
  for (int j = 0; j < 4; ++j){
    srow[j] = (wid * 4 + j) * 8 + sr3;
    ldso[j] = ((wid * 4 + j) * 64 + lane) * 16;    // linear LDS byte offset
  }
  const int ar = wr * 64 + (lane & 15);
  const int br = wc * 64 + (lane & 15);
  // fragment read (shorts): row*64 + ((ks*4 + (lane>>4)) ^ (lane&7))*8 ;
  // row&7 = lane&7 for all mi/wr since 16|row-offsets.
  const int rch0 = (((lane >> 4)    ) ^ (lane & 7)) * 8;   // ks=0
  const int rch1 = (((lane >> 4) + 4) ^ (lane & 7)) * 8;   // ks=1

  // prologue: stage tile 0 into buf 0
  #pragma unroll
  for (int j = 0; j < 4; ++j){
    gld16((char*)As[0] + ldso[j], Ag + (size_t)srow[j] * K + scol);
    gld16((char*)Bs[0] + ldso[j], Bg + (size_t)srow[j] * K + scol);
  }
  __syncthreads();                                 // drains vmcnt(0)

  const int NIT = K >> 6;                          // 12
  int cur = 0;
  for (int it = 0; it < NIT; ++it){
    if (it + 1 < NIT){                             // stage next tile first
      const int k0 = (it + 1) << 6;
      char* An = (char*)As[cur ^ 1]; char* Bn = (char*)Bs[cur ^ 1];
      #pragma unroll
      for (int j = 0; j < 4; ++j){
        gld16(An + ldso[j], Ag + (size_t)srow[j] * K + k0 + scol);
        gld16(Bn + ldso[j], Bg + (size_t)srow[j] * K + k0 + scol);
      }
    }
    const unsigned short* Ac = As[cur];
    const unsigned short* Bc = Bs[cur];
    #pragma unroll
    for (int ks = 0; ks < 2; ++ks){
      const int rch = ks ? rch1 : rch0;
      s16x8 af[4], bf[4];
      #pragma unroll
      for (int mi = 0; mi < 4; ++mi) af[mi] = *(const s16x8*)&Ac[(ar + mi * 16) * 64 + rch];
      #pragma unroll
      for (int ni = 0; ni < 4; ++ni) bf[ni] = *(const s16x8*)&Bc[(br + ni * 16) * 64 + rch];
      #pragma unroll
      for (int mi = 0; mi < 4; ++mi)
        #pragma unroll
        for (int ni = 0; ni < 4; ++ni)
          acc[mi][ni] = mfma16(af[mi], bf[ni], acc[mi][ni]);
    }
    __syncthreads();   // reads of buf[cur] done + stage of buf[cur^1] landed
    cur ^= 1;
  }

  const int row0 = bm * 128 + wr * 64;
  const int col0 = bn * 128 + wc * 64;
  if (MODE == 0){
    #pragma unroll
    for (int ni = 0; ni < 4; ++ni){
      int col = col0 + ni * 16 + (lane & 15);
      int s = col / CC, rem = col - s * CC;
      int h = rem >> 6, d = rem & 63;
      #pragma unroll
      for (int mi = 0; mi < 4; ++mi){
        int rbase = row0 + mi * 16 + ((lane >> 4) << 2);
        int b = rbase >> 11, tok0 = rbase & 2047;
        if (s == 0){
          size_t base = (((size_t)(b * HH + h) << 11) + tok0) * DD + d;
          #pragma unroll
          for (int r = 0; r < 4; ++r) Qg[base + (size_t)r * DD] = f2bf(acc[mi][ni][r] * QSCALE);
        } else {
          int4 cj4 = *(const int4*)&cmap[rbase];
          #pragma unroll
          for (int r = 0; r < 4; ++r){
            int cj = (&cj4.x)[r];
            if (cj >= 0){
              if (s == 1)
                Kg [((size_t)(b * HH + h) * NN + cj) * DD + d] = f2bf(acc[mi][ni][r]);
              else
                Vtg[((size_t)(b * HH + h) * DD + d) * NN + cj] = f2bf(acc[mi][ni][r]);
            }
          }
        }
      }
    }
  } else {
    #pragma unroll
    for (int ni = 0; ni < 4; ++ni){
      int col = col0 + ni * 16 + (lane & 15);
      #pragma unroll
      for (int mi = 0; mi < 4; ++mi){
        int rbase = row0 + mi * 16 + ((lane >> 4) << 2);
        #pragma unroll
        for (int r = 0; r < 4; ++r) Outg[(size_t)(rbase + r) * Nn + col] = acc[mi][ni][r];
      }
    }
  }
}

// exp2 + RNE pack via v_cvt_pk_bf16_f32; l accumulated as float2 (v_pk_add_f32)
__device__ __forceinline__ void packrow2(float s0, float s1, float s2, float s3,
                                         f32x2& l2, unsigned& d0, unsigned& d1){
  float p0 = fexp2(s0), p1 = fexp2(s1), p2 = fexp2(s2), p3 = fexp2(s3);
  f32x2 a = {p0, p1}, b = {p2, p3};
  l2 += a + b;
  asm("v_cvt_pk_bf16_f32 %0, %1, %2" : "=v"(d0) : "v"(p0), "v"(p1));
  asm("v_cvt_pk_bf16_f32 %0, %1, %2" : "=v"(d1) : "v"(p2), "v"(p3));
}

// ---- flash attention over COMPACTED kv — byte-identical to r12/r14/r16/r17
// (verified): loop bound ntile[b] (~17 vs 32), l-correction npadf[b].
__global__ __launch_bounds__(256, 3) void attn_kernel(
    const unsigned short* __restrict__ Qg, const unsigned short* __restrict__ Kg,
    const unsigned short* __restrict__ Vtg, const float* __restrict__ mask,
    const int* __restrict__ ntile, const float* __restrict__ npadf,
    unsigned short* __restrict__ Og)
{
  // main loop: Ks 64x72 (9216B) + Vts 64x72 (9216B)
  // epilogue alias: 8192 f32 (o partials) + 128 f32 (l partials) = 33280B
  __shared__ __align__(16) char smem[33280];
  unsigned short* Ks  = (unsigned short*)smem;
  unsigned short* Vts = (unsigned short*)(smem + 9216);   // BYTE offset
  float* fb = (float*)smem;
  __shared__ float maskS[128];

  const int t = threadIdx.x, lane = t & 63, w = t >> 6;
  const int lo5 = lane & 31, hi = lane >> 5, hi8 = hi * 8;
  const int pair = w >> 1, h2 = w & 1;

  // XCD-chunked swizzle: 768 blocks = 8 x 96; all 16 q-tiles of a (b,h)
  // group land on one XCD -> K/V L2-resident per XCD.
  int g = blockIdx.x + (NN / 128) * blockIdx.y;
  g = (g & 7) * 96 + (g >> 3);
  const int qt = g & 15, bh = g >> 4;
  const int b = bh / HH, h = bh % HH;
  const unsigned short* Qb  = Qg  + (size_t)bh * NN * DD;
  const unsigned short* Kb  = Kg  + (size_t)bh * NN * DD;
  const unsigned short* Vtb = Vtg + (size_t)bh * DD * NN;
  const int ntiles = ntile[b];

  // Q fragments (B-operand of swapped QK^T), 2 q-groups of 32 rows
  const int qrow0 = qt * 128 + pair * 64 + lo5;
  s16x8 qf0[4], qf1[4];
  #pragma unroll
  for (int ds = 0; ds < 4; ++ds){
    qf0[ds] = *(const s16x8*)&Qb[(size_t)qrow0 * DD + ds * 16 + hi8];
    qf1[ds] = *(const s16x8*)&Qb[(size_t)(qrow0 + 32) * DD + ds * 16 + hi8];
  }
  if (t < 128) maskS[t] = mask[b * NN + qt * 128 + t];

  // staging: 64x64 tile, thread t handles rows r0, r0+32 (16B chunks)
  const int r0 = t >> 3, k8 = (t & 7) * 8;
  const int r1 = r0 + 32;

  f32x16 o00 = {}, o01 = {}, o10 = {}, o11 = {};   // [qgrp][d-half]
  f32x2 la0 = {0.f, 0.f}, la1 = {0.f, 0.f};

  s16x8 kA = *(const s16x8*)&Kb[(size_t)r0 * DD + k8];
  s16x8 kB = *(const s16x8*)&Kb[(size_t)r1 * DD + k8];
  s16x8 vA = *(const s16x8*)&Vtb[(size_t)r0 * NN + k8];
  s16x8 vB = *(const s16x8*)&Vtb[(size_t)(32 + r0) * NN + k8];

  const int kbase = (h2 * 32 + lo5) * 72 + hi8;     // K frag base (shorts)
  const int vcol  = h2 * 32 + hi8;                  // V frag col base

  for (int tt = 0; tt < ntiles; ++tt){
    *(s16x8*)&Ks [r0 * 72 + k8] = kA;
    *(s16x8*)&Ks [r1 * 72 + k8] = kB;
    *(s16x8*)&Vts[r0 * 72 + k8] = vA;
    *(s16x8*)&Vts[r1 * 72 + k8] = vB;
    __syncthreads();
    if (tt + 1 < ntiles){
      int nk = (tt + 1) * 64;
      kA = *(const s16x8*)&Kb[(size_t)(nk + r0) * DD + k8];
      kB = *(const s16x8*)&Kb[(size_t)(nk + r1) * DD + k8];
      vA = *(const s16x8*)&Vtb[(size_t)r0 * NN + nk + k8];
      vB = *(const s16x8*)&Vtb[(size_t)(32 + r0) * NN + nk + k8];
    }

    // QK^T swapped (kv half only): S^T[kv][q], col=q=lo5
    f32x16 s0 = {}, s1 = {};
    __builtin_amdgcn_s_setprio(1);
    #pragma unroll
    for (int ds = 0; ds < 4; ++ds){
      s16x8 kf = *(const s16x8*)&Ks[kbase + ds * 16];
      s0 = mfma32(kf, qf0[ds], s0);
      s1 = mfma32(kf, qf1[ds], s1);
    }
    __builtin_amdgcn_s_setprio(0);

    unsigned pdw0[8], pdw1[8];
    #pragma unroll
    for (int c = 0; c < 4; ++c){
      packrow2(s0[4*c+0], s0[4*c+1], s0[4*c+2], s0[4*c+3], la0, pdw0[2*c], pdw0[2*c+1]);
      packrow2(s1[4*c+0], s1[4*c+1], s1[4*c+2], s1[4*c+3], la1, pdw1[2*c], pdw1[2*c+1]);
    }

    // P-exchange + PV (2 k-slices of 16 in this wave's kv half)
    __builtin_amdgcn_s_setprio(1);
    #pragma unroll
    for (int sl = 0; sl < 2; ++sl){
      const int bb2 = sl * 4;
      unsigned X0 = pdw0[bb2+0], X1 = pdw0[bb2+1], Y0 = pdw0[bb2+2], Y1 = pdw0[bb2+3];
      asm("s_nop 0\n\tv_permlane32_swap_b32 %0, %1" : "+v"(X0), "+v"(Y0));
      asm("s_nop 0\n\tv_permlane32_swap_b32 %0, %1" : "+v"(X1), "+v"(Y1));
      union { unsigned u[4]; s16x8 v; } pa0;
      pa0.u[0] = X0; pa0.u[1] = X1; pa0.u[2] = Y0; pa0.u[3] = Y1;
      unsigned Z0 = pdw1[bb2+0], Z1 = pdw1[bb2+1], W0 = pdw1[bb2+2], W1 = pdw1[bb2+3];
      asm("s_nop 0\n\tv_permlane32_swap_b32 %0, %1" : "+v"(Z0), "+v"(W0));
      asm("s_nop 0\n\tv_permlane32_swap_b32 %0, %1" : "+v"(Z1), "+v"(W1));
      union { unsigned u[4]; s16x8 v; } pa1;
      pa1.u[0] = Z0; pa1.u[1] = Z1; pa1.u[2] = W0; pa1.u[3] = W1;
      s16x8 vfA = *(const s16x8*)&Vts[(size_t)lo5 * 72 + vcol + sl * 16];        // d 0..31
      s16x8 vfB = *(const s16x8*)&Vts[(size_t)(32 + lo5) * 72 + vcol + sl * 16]; // d 32..63
      o00 = mfma32(pa0.v, vfA, o00);
      o01 = mfma32(pa0.v, vfB, o01);
      o10 = mfma32(pa1.v, vfA, o10);
      o11 = mfma32(pa1.v, vfB, o11);
    }
    __builtin_amdgcn_s_setprio(0);
    __syncthreads();
  }

  // l partial per q (this wave's kv half): sum own 16 + partner-hi 16
  float lw0 = la0.x + la0.y; lw0 += __shfl_xor(lw0, 32);
  float lw1 = la1.x + la1.y; lw1 += __shfl_xor(lw1, 32);

  __syncthreads();                       // main-loop LDS reads done
  if (h2 == 1){                          // odd wave: publish partials
    const int ob = pair * 4096 + lane * 16;
    *(f32x16*)&fb[ob +    0] = o00;
    *(f32x16*)&fb[ob + 1024] = o01;
    *(f32x16*)&fb[ob + 2048] = o10;
    *(f32x16*)&fb[ob + 3072] = o11;
    if (hi == 0){
      fb[8192 + pair * 64 + lo5]      = lw0;
      fb[8192 + pair * 64 + 32 + lo5] = lw1;
    }
  }
  __syncthreads();
  if (h2 == 0){                          // even wave: combine + normalize + store
    const int ob = pair * 4096 + lane * 16;
    o00 += *(const f32x16*)&fb[ob +    0];
    o01 += *(const f32x16*)&fb[ob + 1024];
    o10 += *(const f32x16*)&fb[ob + 2048];
    o11 += *(const f32x16*)&fb[ob + 3072];
    float npad = npadf[b];
    lw0 = lw0 + fb[8192 + pair * 64 + lo5]      - npad;
    lw1 = lw1 + fb[8192 + pair * 64 + 32 + lo5] - npad;
    #pragma unroll
    for (int i = 0; i < 16; ++i){
      int q_ = (i & 3) + 8 * (i >> 2) + 4 * hi;
      int qg0 = qt * 128 + pair * 64 + q_;
      float lq0 = __shfl(lw0, q_);
      float mq0 = maskS[pair * 64 + q_];
      size_t base0 = ((size_t)b * NN + qg0) * CC + h * DD + lo5;
      if (mq0 != 0.f){
        float inv0 = mq0 / lq0;
        Og[base0]      = f2bf(o00[i] * inv0);
        Og[base0 + 32] = f2bf(o01[i] * inv0);
      } else {
        Og[base0] = 0; Og[base0 + 32] = 0;
      }
      float lq1 = __shfl(lw1, q_);
      float mq1 = maskS[pair * 64 + 32 + q_];
      size_t base1 = base0 + (size_t)32 * CC;
      if (mq1 != 0.f){
        float inv1 = mq1 / lq1;
        Og[base1]      = f2bf(o10[i] * inv1);
        Og[base1 + 32] = f2bf(o11[i] * inv1);
      } else {
        Og[base1] = 0; Og[base1 + 32] = 0;
      }
    }
  }
}

extern "C" void kernel_launch(void* const* d_in, const int* in_sizes, int n_in,
                              void* d_out, int out_size, void* d_ws, size_t ws_size,
                              hipStream_t stream){
  const float* x     = (const float*)d_in[0];
  const float* mask  = (const float*)d_in[1];
  const float* wqkv  = (const float*)d_in[2];
  const float* wproj = (const float*)d_in[3];
  float* out = (float*)d_out;
  char* ws = (char*)d_ws;
  size_t off = 0;
  auto alloc = [&](size_t bytes) -> void* {
    void* p = ws + off; off += (bytes + 255) & ~(size_t)255; return p;
  };
  unsigned short* xm  = (unsigned short*)alloc((size_t)BB * NN * CC * 2);
  unsigned short* wqb = (unsigned short*)alloc((size_t)3 * CC * CC * 2);
  unsigned short* wpb = (unsigned short*)alloc((size_t)CC * CC * 2);
  unsigned short* Qg  = (unsigned short*)alloc((size_t)BB * HH * NN * DD * 2);
  unsigned short* Kg  = (unsigned short*)alloc((size_t)BB * HH * NN * DD * 2);
  unsigned short* Vtg = (unsigned short*)alloc((size_t)BB * HH * NN * DD * 2);
  unsigned short* Og  = (unsigned short*)alloc((size_t)BB * NN * CC * 2);
  int* cmap           = (int*)alloc((size_t)BB * NN * sizeof(int));
  int* ntile          = (int*)alloc(BB * sizeof(int));
  float* npadf        = (float*)alloc(BB * sizeof(float));

  hipLaunchKernelGGL(prep_all, dim3(PX_BLOCKS + PW_BLOCKS + 1), dim3(256), 0, stream,
                     x, mask, wqkv, wproj, xm, wqb, wpb, cmap, ntile, npadf);
  hipLaunchKernelGGL(padzero, dim3(BB * HH), dim3(256), 0, stream,
                     ntile, npadf, Kg, Vtg);
  hipLaunchKernelGGL(gemm_bt<0>, dim3(BB * NN / 128, 3 * CC / 128), dim3(256), 0, stream,
                     xm, wqb, 3 * CC, CC, Qg, Kg, Vtg, (float*)nullptr, cmap);
  hipLaunchKernelGGL(attn_kernel, dim3(NN / 128, BB * HH), dim3(256), 0, stream,
                     Qg, Kg, Vtg, mask, ntile, npadf, Og);
  hipLaunchKernelGGL(gemm_bt<1>, dim3(BB * NN / 128, CC / 128), dim3(256), 0, stream,
                     Og, wpb, CC, CC, (unsigned short*)nullptr, (unsigned short*)nullptr,
                     (unsigned short*)nullptr, out, cmap);
}

// Round 20
// 127.274 us; speedup vs baseline: 1.0665x; 1.0594x over previous
//
#include <hip/hip_runtime.h>
#include <stdint.h>

#define BB 4
#define NN 2048
#define CC 768
#define HH 12
#define DD 64
#define QSCALE 0.18033688011112042f   // D^-0.5 * log2(e), folded into Q

typedef __attribute__((ext_vector_type(2))) float f32x2;
typedef __attribute__((ext_vector_type(4))) float f32x4;
typedef __attribute__((ext_vector_type(16))) float f32x16;
typedef __attribute__((ext_vector_type(8))) short s16x8;

__device__ __forceinline__ unsigned short f2bf(float f){
  unsigned int x = __float_as_uint(f);
  x += 0x7fffu + ((x >> 16) & 1u);          // round-to-nearest-even
  return (unsigned short)(x >> 16);
}

__device__ __forceinline__ f32x4 mfma16(s16x8 a, s16x8 b, f32x4 c){
  return __builtin_amdgcn_mfma_f32_16x16x32_bf16(a, b, c, 0, 0, 0);
}
__device__ __forceinline__ f32x16 mfma32(s16x8 a, s16x8 b, f32x16 c){
  return __builtin_amdgcn_mfma_f32_32x32x16_bf16(a, b, c, 0, 0, 0);
}

__device__ __forceinline__ float fexp2(float x){
#if __has_builtin(__builtin_amdgcn_exp2f)
  return __builtin_amdgcn_exp2f(x);
#else
  float r; asm("v_exp_f32 %0, %1\n\ts_nop 1" : "=v"(r) : "v"(x)); return r;
#endif
}

__device__ __forceinline__ void gld16(void* lds, const void* g){
  __builtin_amdgcn_global_load_lds(
      (const __attribute__((address_space(1))) unsigned int*)g,
      (__attribute__((address_space(3))) unsigned int*)lds, 16, 0, 0);
}

// ---- fused prep: [0,6144) xm = bf16(x*mask); [6144,8448) cast weights;
//      [8448] compaction scan (cmap, ntile, npadf);
//      [8449,8497) padzero (SELF-COUNTING — no dependency on scan block)
#define PX_BLOCKS 6144            // BB*NN*CC/4/256
#define PW_BLOCKS 2304            // 4*CC*CC/4/256
__global__ void prep_all(const float* __restrict__ x, const float* __restrict__ mask,
                         const float* __restrict__ wq, const float* __restrict__ wp,
                         unsigned short* __restrict__ xm,
                         unsigned short* __restrict__ oq, unsigned short* __restrict__ op,
                         int* __restrict__ cmap, int* __restrict__ ntile,
                         float* __restrict__ npadf,
                         unsigned short* __restrict__ Kg, unsigned short* __restrict__ Vtg){
  const int blk = blockIdx.x, t = threadIdx.x;
  if (blk < PX_BLOCKS){
    int i = blk * 256 + t;                         // float4 group index
    float4 v = ((const float4*)x)[i];
    float m = mask[i / 192];                       // 768/4 = 192 groups per row
    ushort4 o;
    o.x = f2bf(v.x * m); o.y = f2bf(v.y * m);
    o.z = f2bf(v.z * m); o.w = f2bf(v.w * m);
    *(ushort4*)&xm[i * 4] = o;
  } else if (blk < PX_BLOCKS + PW_BLOCKS){
    int i = (blk - PX_BLOCKS) * 256 + t;
    const int nq = (3 * CC * CC) / 4;
    const float4* s; unsigned short* d; int j;
    if (i < nq){ s = (const float4*)wq; d = oq; j = i; }
    else       { s = (const float4*)wp; d = op; j = i - nq; }
    float4 v = s[j];
    ushort4 o;
    o.x = f2bf(v.x); o.y = f2bf(v.y); o.z = f2bf(v.z); o.w = f2bf(v.w);
    *(ushort4*)&d[j * 4] = o;
  } else if (blk == PX_BLOCKS + PW_BLOCKS){
    // per-batch compaction: wave wv covers exactly batch wv (64 thr x 32 tok
    // = 2048). cmap[tok] = within-batch compact pos (or -1 if masked).
    const int ln = t & 63, wv = t >> 6;
    const int base = t * 32;
    int cnt = 0;
    #pragma unroll
    for (int j = 0; j < 32; ++j) cnt += (mask[base + j] != 0.f) ? 1 : 0;
    int v = cnt;                                   // wave inclusive scan
    #pragma unroll
    for (int off = 1; off < 64; off <<= 1){
      int u = __shfl_up(v, off);
      if (ln >= off) v += u;
    }
    __shared__ int wsum[4];
    if (ln == 63) wsum[wv] = v;                    // batch count
    int o2 = v - cnt;                              // within-batch excl prefix
    for (int j = 0; j < 32; ++j){
      int tok = base + j;
      cmap[tok] = (mask[tok] != 0.f) ? o2++ : -1;
    }
    __syncthreads();
    if (t < BB){
      int nb = wsum[t];
      int nt = (nb + 63) >> 6;
      ntile[t] = nt;
      npadf[t] = (float)(nt * 64 - nb);            // pad keys (each adds 1 to l)
    }
  } else {
    // padzero for bh = blk - (scan block + 1): zero ONLY the read-but-
    // unwritten pad region [nact, ntile*64) of compacted K/Vt. Recomputes
    // its batch count itself (2048 mask reads) so it has NO dependency on
    // the scan block (inter-block ordering is undefined — G16).
    const int bh = blk - (PX_BLOCKS + PW_BLOCKS + 1);
    const int b = bh / HH;
    int cnt = 0;
    for (int i = t; i < NN; i += 256) cnt += (mask[b * NN + i] != 0.f) ? 1 : 0;
    #pragma unroll
    for (int off = 1; off < 64; off <<= 1) cnt += __shfl_xor(cnt, off);
    __shared__ int red[4];
    if ((t & 63) == 0) red[t >> 6] = cnt;
    __syncthreads();
    const int nb = red[0] + red[1] + red[2] + red[3];
    const int nt = (nb + 63) >> 6;
    const int npad = nt * 64 - nb;
    if (npad == 0) return;
    unsigned short* Kb = Kg + (size_t)bh * NN * DD + (size_t)nb * DD;
    for (int i = t; i < npad * DD; i += 256) Kb[i] = 0;        // contiguous
    unsigned short* Vb = Vtg + (size_t)bh * DD * NN;
    for (int i = t; i < npad * DD; i += 256){
      int d = i / npad, c = i - d * npad;
      Vb[(size_t)d * NN + nb + c] = 0;
    }
  }
}

// ---- C = A(row-major [M,K]) * B^T (B row-major [Nn,K]), bf16 MFMA -------
// EXACT r17 build (verified best, 129.0us): BK=32, single-barrier dbuf
// (r16, -3.5us), both-sides XOR swizzle (r17, conflicts 3.54M -> 0).
// qkv GEMM ledger — CLOSED at this structure: conflicts not the limit
// (r17 null), occupancy not the limit (r18 M64: occ 2x, +6.7us), BK=64
// worse both unswizzled (r15, conflicts 3x) and swizzled (r19, 64KB LDS
// -> 15% occ, +5.8us). ~480 TF on this short-K shape, above the m102
// curve for comparable size — at the 2-phase structure plateau.
template<int MODE>
__global__ __launch_bounds__(256) void gemm_bt(
    const unsigned short* __restrict__ A, const unsigned short* __restrict__ Bw,
    int Nn, int K,
    unsigned short* __restrict__ Qg, unsigned short* __restrict__ Kg,
    unsigned short* __restrict__ Vtg, float* __restrict__ Outg,
    const int* __restrict__ cmap)
{
  __shared__ __align__(16) unsigned short As[2][128 * 32];
  __shared__ __align__(16) unsigned short Bs[2][128 * 32];
  const int t = threadIdx.x, lane = t & 63, wid = t >> 6;
  const int wr = wid >> 1, wc = wid & 1;
  const int bm = blockIdx.x, bn = blockIdx.y;
  const unsigned short* Ag = A  + (size_t)bm * 128 * K;
  const unsigned short* Bg = Bw + (size_t)bn * 128 * K;
  f32x4 acc[4][4] = {};
  const int srow = wid * 32 + (lane >> 2);
  // staging source chunk swizzle: LDS chunk (row, c) holds global chunk
  // c ^ ((row>>1)&3); (row>>1)&3 = (lane>>3)&3 here.
  const int scol = ((lane & 3) ^ ((lane >> 3) & 3)) * 8;
  const int ar = wr * 64 + (lane & 15);
  const int br = wc * 64 + (lane & 15);
  // read chunk swizzle: (row>>1)&3 = (lane>>1)&3, mi/wr-independent.
  const int kks = ((lane >> 4) ^ ((lane >> 1) & 3)) * 8;
  const int so0 = wid * 2048 + lane * 16;          // LDS byte offsets (m104)
  const int so1 = so0 + 1024;

  // prologue: stage tile 0 into buf 0
  gld16((char*)As[0] + so0, Ag + (size_t)srow * K        + scol);
  gld16((char*)As[0] + so1, Ag + (size_t)(srow + 16) * K + scol);
  gld16((char*)Bs[0] + so0, Bg + (size_t)srow * K        + scol);
  gld16((char*)Bs[0] + so1, Bg + (size_t)(srow + 16) * K + scol);
  __syncthreads();                                 // drains vmcnt(0)

  const int NIT = K >> 5;
  int cur = 0;
  for (int it = 0; it < NIT; ++it){
    if (it + 1 < NIT){                             // stage next tile first:
      const int k0 = (it + 1) << 5;                // loads fly under MFMAs
      char* An = (char*)As[cur ^ 1]; char* Bn = (char*)Bs[cur ^ 1];
      gld16(An + so0, Ag + (size_t)srow * K        + k0 + scol);
      gld16(An + so1, Ag + (size_t)(srow + 16) * K + k0 + scol);
      gld16(Bn + so0, Bg + (size_t)srow * K        + k0 + scol);
      gld16(Bn + so1, Bg + (size_t)(srow + 16) * K + k0 + scol);
    }
    const unsigned short* Ac = As[cur];
    const unsigned short* Bc = Bs[cur];
    s16x8 af[4], bf[4];
    #pragma unroll
    for (int mi = 0; mi < 4; ++mi) af[mi] = *(const s16x8*)&Ac[(ar + mi * 16) * 32 + kks];
    #pragma unroll
    for (int ni = 0; ni < 4; ++ni) bf[ni] = *(const s16x8*)&Bc[(br + ni * 16) * 32 + kks];
    #pragma unroll
    for (int mi = 0; mi < 4; ++mi)
      #pragma unroll
      for (int ni = 0; ni < 4; ++ni)
        acc[mi][ni] = mfma16(af[mi], bf[ni], acc[mi][ni]);
    __syncthreads();   // reads of buf[cur] done + stage of buf[cur^1] landed
    cur ^= 1;
  }

  const int row0 = bm * 128 + wr * 64;
  const int col0 = bn * 128 + wc * 64;
  if (MODE == 0){
    #pragma unroll
    for (int ni = 0; ni < 4; ++ni){
      int col = col0 + ni * 16 + (lane & 15);
      int s = col / CC, rem = col - s * CC;
      int h = rem >> 6, d = rem & 63;
      #pragma unroll
      for (int mi = 0; mi < 4; ++mi){
        int rbase = row0 + mi * 16 + ((lane >> 4) << 2);
        int b = rbase >> 11, tok0 = rbase & 2047;
        if (s == 0){
          size_t base = (((size_t)(b * HH + h) << 11) + tok0) * DD + d;
          #pragma unroll
          for (int r = 0; r < 4; ++r) Qg[base + (size_t)r * DD] = f2bf(acc[mi][ni][r] * QSCALE);
        } else {
          int4 cj4 = *(const int4*)&cmap[rbase];
          #pragma unroll
          for (int r = 0; r < 4; ++r){
            int cj = (&cj4.x)[r];
            if (cj >= 0){
              if (s == 1)
                Kg [((size_t)(b * HH + h) * NN + cj) * DD + d] = f2bf(acc[mi][ni][r]);
              else
                Vtg[((size_t)(b * HH + h) * DD + d) * NN + cj] = f2bf(acc[mi][ni][r]);
            }
          }
        }
      }
    }
  } else {
    #pragma unroll
    for (int ni = 0; ni < 4; ++ni){
      int col = col0 + ni * 16 + (lane & 15);
      #pragma unroll
      for (int mi = 0; mi < 4; ++mi){
        int rbase = row0 + mi * 16 + ((lane >> 4) << 2);
        #pragma unroll
        for (int r = 0; r < 4; ++r) Outg[(size_t)(rbase + r) * Nn + col] = acc[mi][ni][r];
      }
    }
  }
}

// exp2 + RNE pack via v_cvt_pk_bf16_f32; l accumulated as float2 (v_pk_add_f32)
__device__ __forceinline__ void packrow2(float s0, float s1, float s2, float s3,
                                         f32x2& l2, unsigned& d0, unsigned& d1){
  float p0 = fexp2(s0), p1 = fexp2(s1), p2 = fexp2(s2), p3 = fexp2(s3);
  f32x2 a = {p0, p1}, b = {p2, p3};
  l2 += a + b;
  asm("v_cvt_pk_bf16_f32 %0, %1, %2" : "=v"(d0) : "v"(p0), "v"(p1));
  asm("v_cvt_pk_bf16_f32 %0, %1, %2" : "=v"(d1) : "v"(p2), "v"(p3));
}

// ---- flash attention over COMPACTED kv — byte-identical to r12..r17
// (verified): loop bound ntile[b] (~17 vs 32), l-correction npadf[b].
__global__ __launch_bounds__(256, 3) void attn_kernel(
    const unsigned short* __restrict__ Qg, const unsigned short* __restrict__ Kg,
    const unsigned short* __restrict__ Vtg, const float* __restrict__ mask,
    const int* __restrict__ ntile, const float* __restrict__ npadf,
    unsigned short* __restrict__ Og)
{
  // main loop: Ks 64x72 (9216B) + Vts 64x72 (9216B)
  // epilogue alias: 8192 f32 (o partials) + 128 f32 (l partials) = 33280B
  __shared__ __align__(16) char smem[33280];
  unsigned short* Ks  = (unsigned short*)smem;
  unsigned short* Vts = (unsigned short*)(smem + 9216);   // BYTE offset
  float* fb = (float*)smem;
  __shared__ float maskS[128];

  const int t = threadIdx.x, lane = t & 63, w = t >> 6;
  const int lo5 = lane & 31, hi = lane >> 5, hi8 = hi * 8;
  const int pair = w >> 1, h2 = w & 1;

  // XCD-chunked swizzle: 768 blocks = 8 x 96; all 16 q-tiles of a (b,h)
  // group land on one XCD -> K/V L2-resident per XCD.
  int g = blockIdx.x + (NN / 128) * blockIdx.y;
  g = (g & 7) * 96 + (g >> 3);
  const int qt = g & 15, bh = g >> 4;
  const int b = bh / HH, h = bh % HH;
  const unsigned short* Qb  = Qg  + (size_t)bh * NN * DD;
  const unsigned short* Kb  = Kg  + (size_t)bh * NN * DD;
  const unsigned short* Vtb = Vtg + (size_t)bh * DD * NN;
  const int ntiles = ntile[b];

  // Q fragments (B-operand of swapped QK^T), 2 q-groups of 32 rows
  const int qrow0 = qt * 128 + pair * 64 + lo5;
  s16x8 qf0[4], qf1[4];
  #pragma unroll
  for (int ds = 0; ds < 4; ++ds){
    qf0[ds] = *(const s16x8*)&Qb[(size_t)qrow0 * DD + ds * 16 + hi8];
    qf1[ds] = *(const s16x8*)&Qb[(size_t)(qrow0 + 32) * DD + ds * 16 + hi8];
  }
  if (t < 128) maskS[t] = mask[b * NN + qt * 128 + t];

  // staging: 64x64 tile, thread t handles rows r0, r0+32 (16B chunks)
  const int r0 = t >> 3, k8 = (t & 7) * 8;
  const int r1 = r0 + 32;

  f32x16 o00 = {}, o01 = {}, o10 = {}, o11 = {};   // [qgrp][d-half]
  f32x2 la0 = {0.f, 0.f}, la1 = {0.f, 0.f};

  s16x8 kA = *(const s16x8*)&Kb[(size_t)r0 * DD + k8];
  s16x8 kB = *(const s16x8*)&Kb[(size_t)r1 * DD + k8];
  s16x8 vA = *(const s16x8*)&Vtb[(size_t)r0 * NN + k8];
  s16x8 vB = *(const s16x8*)&Vtb[(size_t)(32 + r0) * NN + k8];

  const int kbase = (h2 * 32 + lo5) * 72 + hi8;     // K frag base (shorts)
  const int vcol  = h2 * 32 + hi8;                  // V frag col base

  for (int tt = 0; tt < ntiles; ++tt){
    *(s16x8*)&Ks [r0 * 72 + k8] = kA;
    *(s16x8*)&Ks [r1 * 72 + k8] = kB;
    *(s16x8*)&Vts[r0 * 72 + k8] = vA;
    *(s16x8*)&Vts[r1 * 72 + k8] = vB;
    __syncthreads();
    if (tt + 1 < ntiles){
      int nk = (tt + 1) * 64;
      kA = *(const s16x8*)&Kb[(size_t)(nk + r0) * DD + k8];
      kB = *(const s16x8*)&Kb[(size_t)(nk + r1) * DD + k8];
      vA = *(const s16x8*)&Vtb[(size_t)r0 * NN + nk + k8];
      vB = *(const s16x8*)&Vtb[(size_t)(32 + r0) * NN + nk + k8];
    }

    // QK^T swapped (kv half only): S^T[kv][q], col=q=lo5
    f32x16 s0 = {}, s1 = {};
    __builtin_amdgcn_s_setprio(1);
    #pragma unroll
    for (int ds = 0; ds < 4; ++ds){
      s16x8 kf = *(const s16x8*)&Ks[kbase + ds * 16];
      s0 = mfma32(kf, qf0[ds], s0);
      s1 = mfma32(kf, qf1[ds], s1);
    }
    __builtin_amdgcn_s_setprio(0);

    unsigned pdw0[8], pdw1[8];
    #pragma unroll
    for (int c = 0; c < 4; ++c){
      packrow2(s0[4*c+0], s0[4*c+1], s0[4*c+2], s0[4*c+3], la0, pdw0[2*c], pdw0[2*c+1]);
      packrow2(s1[4*c+0], s1[4*c+1], s1[4*c+2], s1[4*c+3], la1, pdw1[2*c], pdw1[2*c+1]);
    }

    // P-exchange + PV (2 k-slices of 16 in this wave's kv half)
    __builtin_amdgcn_s_setprio(1);
    #pragma unroll
    for (int sl = 0; sl < 2; ++sl){
      const int bb2 = sl * 4;
      unsigned X0 = pdw0[bb2+0], X1 = pdw0[bb2+1], Y0 = pdw0[bb2+2], Y1 = pdw0[bb2+3];
      asm("s_nop 0\n\tv_permlane32_swap_b32 %0, %1" : "+v"(X0), "+v"(Y0));
      asm("s_nop 0\n\tv_permlane32_swap_b32 %0, %1" : "+v"(X1), "+v"(Y1));
      union { unsigned u[4]; s16x8 v; } pa0;
      pa0.u[0] = X0; pa0.u[1] = X1; pa0.u[2] = Y0; pa0.u[3] = Y1;
      unsigned Z0 = pdw1[bb2+0], Z1 = pdw1[bb2+1], W0 = pdw1[bb2+2], W1 = pdw1[bb2+3];
      asm("s_nop 0\n\tv_permlane32_swap_b32 %0, %1" : "+v"(Z0), "+v"(W0));
      asm("s_nop 0\n\tv_permlane32_swap_b32 %0, %1" : "+v"(Z1), "+v"(W1));
      union { unsigned u[4]; s16x8 v; } pa1;
      pa1.u[0] = Z0; pa1.u[1] = Z1; pa1.u[2] = W0; pa1.u[3] = W1;
      s16x8 vfA = *(const s16x8*)&Vts[(size_t)lo5 * 72 + vcol + sl * 16];        // d 0..31
      s16x8 vfB = *(const s16x8*)&Vts[(size_t)(32 + lo5) * 72 + vcol + sl * 16]; // d 32..63
      o00 = mfma32(pa0.v, vfA, o00);
      o01 = mfma32(pa0.v, vfB, o01);
      o10 = mfma32(pa1.v, vfA, o10);
      o11 = mfma32(pa1.v, vfB, o11);
    }
    __builtin_amdgcn_s_setprio(0);
    __syncthreads();
  }

  // l partial per q (this wave's kv half): sum own 16 + partner-hi 16
  float lw0 = la0.x + la0.y; lw0 += __shfl_xor(lw0, 32);
  float lw1 = la1.x + la1.y; lw1 += __shfl_xor(lw1, 32);

  __syncthreads();                       // main-loop LDS reads done
  if (h2 == 1){                          // odd wave: publish partials
    const int ob = pair * 4096 + lane * 16;
    *(f32x16*)&fb[ob +    0] = o00;
    *(f32x16*)&fb[ob + 1024] = o01;
    *(f32x16*)&fb[ob + 2048] = o10;
    *(f32x16*)&fb[ob + 3072] = o11;
    if (hi == 0){
      fb[8192 + pair * 64 + lo5]      = lw0;
      fb[8192 + pair * 64 + 32 + lo5] = lw1;
    }
  }
  __syncthreads();
  if (h2 == 0){                          // even wave: combine + normalize + store
    const int ob = pair * 4096 + lane * 16;
    o00 += *(const f32x16*)&fb[ob +    0];
    o01 += *(const f32x16*)&fb[ob + 1024];
    o10 += *(const f32x16*)&fb[ob + 2048];
    o11 += *(const f32x16*)&fb[ob + 3072];
    float npad = npadf[b];
    lw0 = lw0 + fb[8192 + pair * 64 + lo5]      - npad;
    lw1 = lw1 + fb[8192 + pair * 64 + 32 + lo5] - npad;
    #pragma unroll
    for (int i = 0; i < 16; ++i){
      int q_ = (i & 3) + 8 * (i >> 2) + 4 * hi;
      int qg0 = qt * 128 + pair * 64 + q_;
      float lq0 = __shfl(lw0, q_);
      float mq0 = maskS[pair * 64 + q_];
      size_t base0 = ((size_t)b * NN + qg0) * CC + h * DD + lo5;
      if (mq0 != 0.f){
        float inv0 = mq0 / lq0;
        Og[base0]      = f2bf(o00[i] * inv0);
        Og[base0 + 32] = f2bf(o01[i] * inv0);
      } else {
        Og[base0] = 0; Og[base0 + 32] = 0;
      }
      float lq1 = __shfl(lw1, q_);
      float mq1 = maskS[pair * 64 + 32 + q_];
      size_t base1 = base0 + (size_t)32 * CC;
      if (mq1 != 0.f){
        float inv1 = mq1 / lq1;
        Og[base1]      = f2bf(o10[i] * inv1);
        Og[base1 + 32] = f2bf(o11[i] * inv1);
      } else {
        Og[base1] = 0; Og[base1 + 32] = 0;
      }
    }
  }
}

extern "C" void kernel_launch(void* const* d_in, const int* in_sizes, int n_in,
                              void* d_out, int out_size, void* d_ws, size_t ws_size,
                              hipStream_t stream){
  const float* x     = (const float*)d_in[0];
  const float* mask  = (const float*)d_in[1];
  const float* wqkv  = (const float*)d_in[2];
  const float* wproj = (const float*)d_in[3];
  float* out = (float*)d_out;
  char* ws = (char*)d_ws;
  size_t off = 0;
  auto alloc = [&](size_t bytes) -> void* {
    void* p = ws + off; off += (bytes + 255) & ~(size_t)255; return p;
  };
  unsigned short* xm  = (unsigned short*)alloc((size_t)BB * NN * CC * 2);
  unsigned short* wqb = (unsigned short*)alloc((size_t)3 * CC * CC * 2);
  unsigned short* wpb = (unsigned short*)alloc((size_t)CC * CC * 2);
  unsigned short* Qg  = (unsigned short*)alloc((size_t)BB * HH * NN * DD * 2);
  unsigned short* Kg  = (unsigned short*)alloc((size_t)BB * HH * NN * DD * 2);
  unsigned short* Vtg = (unsigned short*)alloc((size_t)BB * HH * NN * DD * 2);
  unsigned short* Og  = (unsigned short*)alloc((size_t)BB * NN * CC * 2);
  int* cmap           = (int*)alloc((size_t)BB * NN * sizeof(int));
  int* ntile          = (int*)alloc(BB * sizeof(int));
  float* npadf        = (float*)alloc(BB * sizeof(float));

  hipLaunchKernelGGL(prep_all, dim3(PX_BLOCKS + PW_BLOCKS + 1 + BB * HH), dim3(256), 0, stream,
                     x, mask, wqkv, wproj, xm, wqb, wpb, cmap, ntile, npadf, Kg, Vtg);
  hipLaunchKernelGGL(gemm_bt<0>, dim3(BB * NN / 128, 3 * CC / 128), dim3(256), 0, stream,
                     xm, wqb, 3 * CC, CC, Qg, Kg, Vtg, (float*)nullptr, cmap);
  hipLaunchKernelGGL(attn_kernel, dim3(NN / 128, BB * HH), dim3(256), 0, stream,
                     Qg, Kg, Vtg, mask, ntile, npadf, Og);
  hipLaunchKernelGGL(gemm_bt<1>, dim3(BB * NN / 128, CC / 128), dim3(256), 0, stream,
                     Og, wpb, CC, CC, (unsigned short*)nullptr, (unsigned short*)nullptr,
                     (unsigned short*)nullptr, out, cmap);
}